// Round 7
// baseline (212.871 us; speedup 1.0000x reference)
//
#include <hip/hip_runtime.h>
#include <hip/hip_bf16.h>
#include <math.h>

// MoE top-2: B=4,S=2048,H=1024,E=8,K=2. fp32 in/out, f16 MFMA compute.
#define TOK 8192
#define HD 1024
#define NE 8
#define SLOTS 17408     // 16384 + per-expert 128-pad
#define NGRP 128        // 64-token scatter groups

typedef _Float16 half8 __attribute__((ext_vector_type(8)));
typedef _Float16 half4v __attribute__((ext_vector_type(4)));
typedef float floatx4 __attribute__((ext_vector_type(4)));

// ---- Fused score + weight-convert (block-role split) ----
__global__ __launch_bounds__(256) void score_cvt(
    const float* __restrict__ x,
    const float* __restrict__ rw,
    const float* __restrict__ rb,
    const float* __restrict__ ew,
    _Float16* __restrict__ xh,
    _Float16* __restrict__ wh,
    int* __restrict__ epair,
    float* __restrict__ w1out,
    int* __restrict__ hist) {          // [NE][NGRP]
  const int tid = threadIdx.x;
  const int blk = blockIdx.x;
  if (blk >= NGRP) {
    const int g = (blk - NGRP) * 256 + tid;
    const float4* src = (const float4*)ew;
    half4v* dst = (half4v*)wh;
#pragma unroll
    for (int j = 0; j < 4; ++j) {
      float4 v = src[g + 524288 * j];
      half4v h = {(_Float16)v.x, (_Float16)v.y, (_Float16)v.z, (_Float16)v.w};
      dst[g + 524288 * j] = h;
    }
    return;
  }
  const int lane = tid & 63;
  const int wid = tid >> 6;
  __shared__ int hcnt[NE];
  if (tid < NE) hcnt[tid] = 0;
  __syncthreads();

  for (int i = 0; i < 16; ++i) {
    const int t = blk * 64 + wid * 16 + i;
    const float4* xp = (const float4*)(x + (size_t)t * HD);
    float4 xr[4];
#pragma unroll
    for (int k = 0; k < 4; ++k) xr[k] = xp[lane + 64 * k];
    _Float16* xo = xh + (size_t)t * HD;
#pragma unroll
    for (int k = 0; k < 4; ++k) {
      half4v h = {(_Float16)xr[k].x, (_Float16)xr[k].y,
                  (_Float16)xr[k].z, (_Float16)xr[k].w};
      *(half4v*)(xo + (lane + 64 * k) * 4) = h;
    }
    float sc[NE];
#pragma unroll
    for (int e = 0; e < NE; ++e) {
      const float4* wp = (const float4*)(rw + e * HD);
      float a = 0.f;
#pragma unroll
      for (int k = 0; k < 4; ++k) {
        float4 w = wp[lane + 64 * k];
        a += xr[k].x * w.x + xr[k].y * w.y + xr[k].z * w.z + xr[k].w * w.w;
      }
#pragma unroll
      for (int off = 32; off > 0; off >>= 1) a += __shfl_xor(a, off);
      sc[e] = a + rb[e];
    }
    // top-2, strict > (ties -> lowest index, matches jax.lax.top_k)
    float b1 = sc[0]; int e1 = 0;
#pragma unroll
    for (int e = 1; e < NE; ++e) if (sc[e] > b1) { b1 = sc[e]; e1 = e; }
    float b2 = -1e30f; int e2 = 0;
#pragma unroll
    for (int e = 0; e < NE; ++e) { if (e != e1 && sc[e] > b2) { b2 = sc[e]; e2 = e; } }
    if (lane == 0) {
      epair[t] = e1 | (e2 << 8);
      w1out[t] = 1.f / (1.f + expf(b2 - b1));  // renormalized top-2 softmax
      atomicAdd(&hcnt[e1], 1);
      atomicAdd(&hcnt[e2], 1);
    }
  }
  __syncthreads();
  if (tid < NE) hist[tid * NGRP + blk] = hcnt[tid];
}

// ---- Scatter: each block recomputes its prefix from hist (no global sync) --
__global__ __launch_bounds__(256) void moe_scatter(
    const int* __restrict__ hist,
    const int* __restrict__ epair,
    const float* __restrict__ w1in,
    int* __restrict__ cntp,
    int* __restrict__ basep,
    int* __restrict__ tok_list,
    float* __restrict__ tok_w,
    int* __restrict__ slot_of) {
  const int tid = threadIdx.x;
  const int blk = blockIdx.x;
  __shared__ int pre_s[NE], tot_s[NE], alloc_s[NE];
  {
    const int e = tid >> 5;
    const int sl = tid & 31;
    int p = 0, tt = 0;
#pragma unroll
    for (int j = 0; j < 4; ++j) {
      int g = sl + 32 * j;
      int h = hist[e * NGRP + g];
      tt += h;
      p += (g < blk) ? h : 0;
    }
#pragma unroll
    for (int off = 16; off > 0; off >>= 1) {
      p += __shfl_xor(p, off);
      tt += __shfl_xor(tt, off);
    }
    if (sl == 0) { pre_s[e] = p; tot_s[e] = tt; }
  }
  __syncthreads();
  if (tid == 0) {
    int b = 0;
    for (int e = 0; e < NE; ++e) {
      alloc_s[e] = b + pre_s[e];
      if (blk == 0) { cntp[e * 64] = tot_s[e]; basep[e] = b; }
      b += (tot_s[e] + 127) & ~127;
    }
  }
  __syncthreads();
  if (tid < 64) {
    const int t = blk * 64 + tid;
    int ep = epair[t];
    int e1 = ep & 0xff, e2 = ep >> 8;
    float w1 = w1in[t];
    int s1 = atomicAdd(&alloc_s[e1], 1);
    tok_list[s1] = t; tok_w[s1] = w1; slot_of[2 * t] = s1;
    int s2 = atomicAdd(&alloc_s[e2], 1);
    tok_list[s2] = t; tok_w[s2] = 1.f - w1; slot_of[2 * t + 1] = s2;
  }
}

// ---- Grouped expert GEMM: 128x128, BK=64, DOUBLE-BUFFERED LDS ----
// One barrier per k-step; next tile's loads issue right after the barrier and
// land during compute (the vmcnt(0)-before-barrier drain coincides with the
// wait we need). LDS 2x32KB+1KB -> 2 blocks/CU.
// EPI=1: f16 store to compacted scratch; EPI=0: fp32 atomicAdd to out.
template <int EPI>
__global__ __launch_bounds__(256, 2) void moe_gemm(
    const _Float16* __restrict__ Ah, const _Float16* __restrict__ Bh,
    const float* __restrict__ eb,
    const int* __restrict__ cntp, const int* __restrict__ base,
    const int* __restrict__ tok_list, const float* __restrict__ tok_w,
    _Float16* __restrict__ scratch, float* __restrict__ out) {
  const int e = blockIdx.z;
  const int ce = cntp[e * 64];
  const int m0 = blockIdx.y << 7;
  if (m0 >= ce) return;
  const int sbase = base[e];
  const int n0 = blockIdx.x << 7;
  const int tid = threadIdx.x;
  const int lane = tid & 63;
  const int wid = tid >> 6;
  const int wm = wid & 1, wn = wid >> 1;

  __shared__ _Float16 A_s[2][128 * 64];
  __shared__ _Float16 B_s[2][128 * 64];
  __shared__ int tok_s[128];
  __shared__ float w_s[128];

  if (tid < 128) {
    int tk = 0; float w = 0.f;
    if (m0 + tid < ce) { tk = tok_list[sbase + m0 + tid]; w = tok_w[sbase + m0 + tid]; }
    tok_s[tid] = tk; w_s[tid] = w;
  }
  __syncthreads();

  floatx4 acc[4][4];
  floatx4 zero = {0.f, 0.f, 0.f, 0.f};
#pragma unroll
  for (int i = 0; i < 4; ++i)
#pragma unroll
    for (int j = 0; j < 4; ++j) acc[i][j] = zero;

  const int wbase = e * HD * HD;   // fits int: <= 7*2^20
  // staging: 4 rounds x 8 rows/wave; lane = rloc*8+sub (16B chunks), XOR swizzle
  const int rloc = lane >> 3, sub = lane & 7;
  const int csw = (sub ^ rloc) * 8;
  int agoff[4], bgoff[4];
#pragma unroll
  for (int q = 0; q < 4; ++q) {
    int row = wid * 32 + q * 8 + rloc;
    agoff[q] = tok_s[row] * HD + csw;
    bgoff[q] = wbase + (n0 + row) * HD + csw;
  }
  const int x7 = lane & 7, q4 = lane >> 4;

  // prologue: stage k0=0 into buffer 0
#pragma unroll
  for (int q = 0; q < 4; ++q) {
    const int r0 = wid * 32 + q * 8;
    __builtin_amdgcn_global_load_lds(
        (const __attribute__((address_space(1))) unsigned int*)(Ah + agoff[q]),
        (__attribute__((address_space(3))) unsigned int*)&A_s[0][r0 * 64], 16, 0, 0);
    __builtin_amdgcn_global_load_lds(
        (const __attribute__((address_space(1))) unsigned int*)(Bh + bgoff[q]),
        (__attribute__((address_space(3))) unsigned int*)&B_s[0][r0 * 64], 16, 0, 0);
  }

  int buf = 0;
  for (int ks = 0; ks < 16; ++ks) {
    // drains vmcnt -> this buffer's loads complete; also fences the other
    // buffer (all waves done reading it) before we overwrite it below.
    __syncthreads();
    if (ks < 15) {
      const int k1 = (ks + 1) * 64;
      const int nb = buf ^ 1;
#pragma unroll
      for (int q = 0; q < 4; ++q) {
        const int r0 = wid * 32 + q * 8;
        __builtin_amdgcn_global_load_lds(
            (const __attribute__((address_space(1))) unsigned int*)(Ah + agoff[q] + k1),
            (__attribute__((address_space(3))) unsigned int*)&A_s[nb][r0 * 64], 16, 0, 0);
        __builtin_amdgcn_global_load_lds(
            (const __attribute__((address_space(1))) unsigned int*)(Bh + bgoff[q] + k1),
            (__attribute__((address_space(3))) unsigned int*)&B_s[nb][r0 * 64], 16, 0, 0);
      }
    }
#pragma unroll
    for (int kf = 0; kf < 2; ++kf) {
      half8 afr[4], bfr[4];
      const int cc = kf * 4 + q4;
#pragma unroll
      for (int i = 0; i < 4; ++i)
        afr[i] = *(const half8*)&A_s[buf][(wm * 64 + i * 16 + (lane & 15)) * 64 + ((cc ^ x7) * 8)];
#pragma unroll
      for (int j = 0; j < 4; ++j)
        bfr[j] = *(const half8*)&B_s[buf][(wn * 64 + j * 16 + (lane & 15)) * 64 + ((cc ^ x7) * 8)];
#pragma unroll
      for (int i = 0; i < 4; ++i)
#pragma unroll
        for (int j = 0; j < 4; ++j)
          acc[i][j] = __builtin_amdgcn_mfma_f32_16x16x32_f16(afr[i], bfr[j], acc[i][j], 0, 0, 0);
    }
    buf ^= 1;
  }

  // epilogue: C/D layout col=lane&15, row=(lane>>4)*4+reg
#pragma unroll
  for (int j = 0; j < 4; ++j) {
    int col = n0 + wn * 64 + j * 16 + (lane & 15);
    float bias = eb[e * HD + col];
#pragma unroll
    for (int i = 0; i < 4; ++i) {
      int rbase = wm * 64 + i * 16 + (q4 << 2);
#pragma unroll
      for (int r = 0; r < 4; ++r) {
        int row = rbase + r;
        float v = w_s[row] * (acc[i][j][r] + bias);
        if (EPI == 1) {
          scratch[(size_t)(sbase + m0 + row) * HD + col] = (_Float16)v;
        } else {
          if (m0 + row < ce)
            atomicAdd(&out[(size_t)tok_s[row] * HD + col], v);
        }
      }
    }
  }
}

// ---- Combine: out[t] = scratch[slot0] + scratch[slot1] ----
__global__ void moe_combine(const _Float16* __restrict__ scratch,
                            const int* __restrict__ slot_of,
                            float* __restrict__ out) {
  const int tid = threadIdx.x;
  const int t = blockIdx.x * 2 + (tid >> 7);
  const int c = (tid & 127) * 8;
  int sa = slot_of[2 * t], sb = slot_of[2 * t + 1];
  half8 a = *(const half8*)&scratch[(size_t)sa * HD + c];
  half8 b = *(const half8*)&scratch[(size_t)sb * HD + c];
  float* o = out + (size_t)t * HD + c;
  float4 o0 = {(float)a[0] + (float)b[0], (float)a[1] + (float)b[1],
               (float)a[2] + (float)b[2], (float)a[3] + (float)b[3]};
  float4 o1 = {(float)a[4] + (float)b[4], (float)a[5] + (float)b[5],
               (float)a[6] + (float)b[6], (float)a[7] + (float)b[7]};
  *(float4*)o = o0;
  *(float4*)(o + 4) = o1;
}

extern "C" void kernel_launch(void* const* d_in, const int* in_sizes, int n_in,
                              void* d_out, int out_size, void* d_ws, size_t ws_size,
                              hipStream_t stream) {
  (void)in_sizes; (void)n_in;
  const float* x  = (const float*)d_in[0];
  const float* rw = (const float*)d_in[1];
  const float* rb = (const float*)d_in[2];
  const float* ew = (const float*)d_in[3];
  const float* eb = (const float*)d_in[4];
  float* out = (float*)d_out;

  // ws layout
  char* w = (char*)d_ws;
  int*   cntp     = (int*)(w + 0);        // NE*64 ints (2 KB)
  int*   basep    = (int*)(w + 2048);     // 8 ints
  int*   hist     = (int*)(w + 2304);     // NE*NGRP ints (4 KB)
  size_t off = 2304 + (size_t)NE * NGRP * 4;
  int*   tok_list = (int*)(w + off);  off += (size_t)SLOTS * 4;
  float* tok_w    = (float*)(w + off); off += (size_t)SLOTS * 4;
  int*   slot_of  = (int*)(w + off);  off += (size_t)TOK * 8;
  int*   epair    = (int*)(w + off);  off += (size_t)TOK * 4;
  float* w1buf    = (float*)(w + off); off += (size_t)TOK * 4;
  off = (off + 255) & ~255ull;
  size_t xh_off = off;
  size_t wh_off = xh_off + (size_t)TOK * HD * 2;
  size_t scr_off = wh_off + (size_t)NE * HD * HD * 2;
  size_t needscr = scr_off + (size_t)SLOTS * HD * 2;
  bool fastscr = ws_size >= needscr;

  if (!fastscr)
    hipMemsetAsync(d_out, 0, (size_t)out_size * sizeof(float), stream);

  _Float16* xh = (_Float16*)(w + xh_off);
  _Float16* wh = (_Float16*)(w + wh_off);
  _Float16* scr = fastscr ? (_Float16*)(w + scr_off) : nullptr;

  score_cvt<<<NGRP + 2048, 256, 0, stream>>>(x, rw, rb, ew, xh, wh,
                                             epair, w1buf, hist);
  moe_scatter<<<NGRP, 256, 0, stream>>>(hist, epair, w1buf, cntp, basep,
                                        tok_list, tok_w, slot_of);

  dim3 grid(HD / 128, TOK / 128, NE);  // (n=8, m<=64, e=8), early-out on m
  if (fastscr) {
    moe_gemm<1><<<grid, 256, 0, stream>>>(xh, wh, eb, cntp, basep,
                                          tok_list, tok_w, scr, out);
    moe_combine<<<TOK / 2, 256, 0, stream>>>(scr, slot_of, out);
  } else {
    moe_gemm<0><<<grid, 256, 0, stream>>>(xh, wh, eb, cntp, basep,
                                          tok_list, tok_w, nullptr, out);
  }
}

// Round 8
// 195.998 us; speedup vs baseline: 1.0861x; 1.0861x over previous
//
#include <hip/hip_runtime.h>
#include <hip/hip_bf16.h>
#include <math.h>

// MoE top-2: B=4,S=2048,H=1024,E=8,K=2. fp32 in/out, f16 MFMA compute.
#define TOK 8192
#define HD 1024
#define NE 8
#define SLOTS 17408     // 16384 + per-expert 128-pad
#define NGRP 128        // 64-token scatter groups

typedef _Float16 half8 __attribute__((ext_vector_type(8)));
typedef _Float16 half4v __attribute__((ext_vector_type(4)));
typedef float floatx4 __attribute__((ext_vector_type(4)));

// ---- Fused score + weight-convert (block-role split) ----
__global__ __launch_bounds__(256) void score_cvt(
    const float* __restrict__ x,
    const float* __restrict__ rw,
    const float* __restrict__ rb,
    const float* __restrict__ ew,
    _Float16* __restrict__ xh,
    _Float16* __restrict__ wh,
    int* __restrict__ epair,
    float* __restrict__ w1out,
    int* __restrict__ hist) {          // [NE][NGRP]
  const int tid = threadIdx.x;
  const int blk = blockIdx.x;
  if (blk >= NGRP) {
    const int g = (blk - NGRP) * 256 + tid;
    const float4* src = (const float4*)ew;
    half4v* dst = (half4v*)wh;
#pragma unroll
    for (int j = 0; j < 4; ++j) {
      float4 v = src[g + 524288 * j];
      half4v h = {(_Float16)v.x, (_Float16)v.y, (_Float16)v.z, (_Float16)v.w};
      dst[g + 524288 * j] = h;
    }
    return;
  }
  const int lane = tid & 63;
  const int wid = tid >> 6;
  __shared__ int hcnt[NE];
  if (tid < NE) hcnt[tid] = 0;
  __syncthreads();

  for (int i = 0; i < 16; ++i) {
    const int t = blk * 64 + wid * 16 + i;
    const float4* xp = (const float4*)(x + (size_t)t * HD);
    float4 xr[4];
#pragma unroll
    for (int k = 0; k < 4; ++k) xr[k] = xp[lane + 64 * k];
    _Float16* xo = xh + (size_t)t * HD;
#pragma unroll
    for (int k = 0; k < 4; ++k) {
      half4v h = {(_Float16)xr[k].x, (_Float16)xr[k].y,
                  (_Float16)xr[k].z, (_Float16)xr[k].w};
      *(half4v*)(xo + (lane + 64 * k) * 4) = h;
    }
    float sc[NE];
#pragma unroll
    for (int e = 0; e < NE; ++e) {
      const float4* wp = (const float4*)(rw + e * HD);
      float a = 0.f;
#pragma unroll
      for (int k = 0; k < 4; ++k) {
        float4 w = wp[lane + 64 * k];
        a += xr[k].x * w.x + xr[k].y * w.y + xr[k].z * w.z + xr[k].w * w.w;
      }
#pragma unroll
      for (int off = 32; off > 0; off >>= 1) a += __shfl_xor(a, off);
      sc[e] = a + rb[e];
    }
    // top-2, strict > (ties -> lowest index, matches jax.lax.top_k)
    float b1 = sc[0]; int e1 = 0;
#pragma unroll
    for (int e = 1; e < NE; ++e) if (sc[e] > b1) { b1 = sc[e]; e1 = e; }
    float b2 = -1e30f; int e2 = 0;
#pragma unroll
    for (int e = 0; e < NE; ++e) { if (e != e1 && sc[e] > b2) { b2 = sc[e]; e2 = e; } }
    if (lane == 0) {
      epair[t] = e1 | (e2 << 8);
      w1out[t] = 1.f / (1.f + expf(b2 - b1));  // renormalized top-2 softmax
      atomicAdd(&hcnt[e1], 1);
      atomicAdd(&hcnt[e2], 1);
    }
  }
  __syncthreads();
  if (tid < NE) hist[tid * NGRP + blk] = hcnt[tid];
}

// ---- Scatter: each block recomputes its prefix from hist (no global sync) --
__global__ __launch_bounds__(256) void moe_scatter(
    const int* __restrict__ hist,
    const int* __restrict__ epair,
    const float* __restrict__ w1in,
    int* __restrict__ cntp,
    int* __restrict__ basep,
    int* __restrict__ tok_list,
    float* __restrict__ tok_w,
    int* __restrict__ slot_of) {
  const int tid = threadIdx.x;
  const int blk = blockIdx.x;
  __shared__ int pre_s[NE], tot_s[NE], alloc_s[NE];
  {
    const int e = tid >> 5;
    const int sl = tid & 31;
    int p = 0, tt = 0;
#pragma unroll
    for (int j = 0; j < 4; ++j) {
      int g = sl + 32 * j;
      int h = hist[e * NGRP + g];
      tt += h;
      p += (g < blk) ? h : 0;
    }
#pragma unroll
    for (int off = 16; off > 0; off >>= 1) {
      p += __shfl_xor(p, off);
      tt += __shfl_xor(tt, off);
    }
    if (sl == 0) { pre_s[e] = p; tot_s[e] = tt; }
  }
  __syncthreads();
  if (tid == 0) {
    int b = 0;
    for (int e = 0; e < NE; ++e) {
      alloc_s[e] = b + pre_s[e];
      if (blk == 0) { cntp[e * 64] = tot_s[e]; basep[e] = b; }
      b += (tot_s[e] + 127) & ~127;
    }
  }
  __syncthreads();
  if (tid < 64) {
    const int t = blk * 64 + tid;
    int ep = epair[t];
    int e1 = ep & 0xff, e2 = ep >> 8;
    float w1 = w1in[t];
    int s1 = atomicAdd(&alloc_s[e1], 1);
    tok_list[s1] = t; tok_w[s1] = w1; slot_of[2 * t] = s1;
    int s2 = atomicAdd(&alloc_s[e2], 1);
    tok_list[s2] = t; tok_w[s2] = 1.f - w1; slot_of[2 * t + 1] = s2;
  }
}

// ---- Grouped expert GEMM: 128x128 tile, BK=128, single-buffer, 8 ksteps ----
// Duration scales with barrier-phase count (R2->R3: 32->16 ksteps halved it),
// so halve again. LDS 65KB -> 2 blocks/CU. 4-bit XOR chunk swizzle:
// staging stores global chunk g at position g^(row&15); fragment reads
// position (cc)^(row&15) -> 2-way bank aliasing only (free).
// EPI=1: f16 store to compacted scratch; EPI=0: fp32 atomicAdd to out.
template <int EPI>
__global__ __launch_bounds__(256, 2) void moe_gemm(
    const _Float16* __restrict__ Ah, const _Float16* __restrict__ Bh,
    const float* __restrict__ eb,
    const int* __restrict__ cntp, const int* __restrict__ base,
    const int* __restrict__ tok_list, const float* __restrict__ tok_w,
    _Float16* __restrict__ scratch, float* __restrict__ out) {
  const int e = blockIdx.z;
  const int ce = cntp[e * 64];
  const int m0 = blockIdx.y << 7;
  if (m0 >= ce) return;
  const int sbase = base[e];
  const int n0 = blockIdx.x << 7;
  const int tid = threadIdx.x;
  const int lane = tid & 63;
  const int wid = tid >> 6;
  const int wm = wid & 1, wn = wid >> 1;

  __shared__ _Float16 A_s[128 * 128];
  __shared__ _Float16 B_s[128 * 128];
  __shared__ int tok_s[128];
  __shared__ float w_s[128];

  if (tid < 128) {
    int tk = 0; float w = 0.f;
    if (m0 + tid < ce) { tk = tok_list[sbase + m0 + tid]; w = tok_w[sbase + m0 + tid]; }
    tok_s[tid] = tk; w_s[tid] = w;
  }
  __syncthreads();

  floatx4 acc[4][4];
  floatx4 zero = {0.f, 0.f, 0.f, 0.f};
#pragma unroll
  for (int i = 0; i < 4; ++i)
#pragma unroll
    for (int j = 0; j < 4; ++j) acc[i][j] = zero;

  const int wbase = e * HD * HD;   // fits int: <= 7*2^20
  // staging: 8 instrs/wave for A (+8 for B); each instr = 4 rows x 16 chunks.
  // lane: rloc = lane>>4 (row within quad), sub = lane&15 (LDS chunk pos).
  // global chunk g = sub ^ (row&15)  => LDS pos p holds chunk p^(row&15).
  const int rloc = lane >> 4, sub = lane & 15;
  int agoff[8], bgoff[8];
#pragma unroll
  for (int q = 0; q < 8; ++q) {
    int row = wid * 32 + q * 4 + rloc;
    int g = sub ^ (row & 15);
    agoff[q] = tok_s[row] * HD + g * 8;
    bgoff[q] = wbase + (n0 + row) * HD + g * 8;
  }
  const int l15 = lane & 15, q4 = lane >> 4;

  for (int k0 = 0; k0 < HD; k0 += 128) {
#pragma unroll
    for (int q = 0; q < 8; ++q) {
      const int r0 = wid * 32 + q * 4;
      __builtin_amdgcn_global_load_lds(
          (const __attribute__((address_space(1))) unsigned int*)(Ah + agoff[q] + k0),
          (__attribute__((address_space(3))) unsigned int*)&A_s[r0 * 128], 16, 0, 0);
      __builtin_amdgcn_global_load_lds(
          (const __attribute__((address_space(1))) unsigned int*)(Bh + bgoff[q] + k0),
          (__attribute__((address_space(3))) unsigned int*)&B_s[r0 * 128], 16, 0, 0);
    }
    __syncthreads();
#pragma unroll
    for (int kf = 0; kf < 4; ++kf) {
      half8 afr[4], bfr[4];
      const int cc = kf * 4 + q4;
#pragma unroll
      for (int i = 0; i < 4; ++i)
        afr[i] = *(const half8*)&A_s[(wm * 64 + i * 16 + l15) * 128 + ((cc ^ l15) * 8)];
#pragma unroll
      for (int j = 0; j < 4; ++j)
        bfr[j] = *(const half8*)&B_s[(wn * 64 + j * 16 + l15) * 128 + ((cc ^ l15) * 8)];
#pragma unroll
      for (int i = 0; i < 4; ++i)
#pragma unroll
        for (int j = 0; j < 4; ++j)
          acc[i][j] = __builtin_amdgcn_mfma_f32_16x16x32_f16(afr[i], bfr[j], acc[i][j], 0, 0, 0);
    }
    __syncthreads();
  }

  // epilogue: C/D layout col=lane&15, row=(lane>>4)*4+reg
#pragma unroll
  for (int j = 0; j < 4; ++j) {
    int col = n0 + wn * 64 + j * 16 + l15;
    float bias = eb[e * HD + col];
#pragma unroll
    for (int i = 0; i < 4; ++i) {
      int rbase = wm * 64 + i * 16 + (q4 << 2);
#pragma unroll
      for (int r = 0; r < 4; ++r) {
        int row = rbase + r;
        float v = w_s[row] * (acc[i][j][r] + bias);
        if (EPI == 1) {
          scratch[(size_t)(sbase + m0 + row) * HD + col] = (_Float16)v;
        } else {
          if (m0 + row < ce)
            atomicAdd(&out[(size_t)tok_s[row] * HD + col], v);
        }
      }
    }
  }
}

// ---- Combine: out[t] = scratch[slot0] + scratch[slot1] ----
__global__ void moe_combine(const _Float16* __restrict__ scratch,
                            const int* __restrict__ slot_of,
                            float* __restrict__ out) {
  const int tid = threadIdx.x;
  const int t = blockIdx.x * 2 + (tid >> 7);
  const int c = (tid & 127) * 8;
  int sa = slot_of[2 * t], sb = slot_of[2 * t + 1];
  half8 a = *(const half8*)&scratch[(size_t)sa * HD + c];
  half8 b = *(const half8*)&scratch[(size_t)sb * HD + c];
  float* o = out + (size_t)t * HD + c;
  float4 o0 = {(float)a[0] + (float)b[0], (float)a[1] + (float)b[1],
               (float)a[2] + (float)b[2], (float)a[3] + (float)b[3]};
  float4 o1 = {(float)a[4] + (float)b[4], (float)a[5] + (float)b[5],
               (float)a[6] + (float)b[6], (float)a[7] + (float)b[7]};
  *(float4*)o = o0;
  *(float4*)(o + 4) = o1;
}

extern "C" void kernel_launch(void* const* d_in, const int* in_sizes, int n_in,
                              void* d_out, int out_size, void* d_ws, size_t ws_size,
                              hipStream_t stream) {
  (void)in_sizes; (void)n_in;
  const float* x  = (const float*)d_in[0];
  const float* rw = (const float*)d_in[1];
  const float* rb = (const float*)d_in[2];
  const float* ew = (const float*)d_in[3];
  const float* eb = (const float*)d_in[4];
  float* out = (float*)d_out;

  // ws layout
  char* w = (char*)d_ws;
  int*   cntp     = (int*)(w + 0);        // NE*64 ints (2 KB)
  int*   basep    = (int*)(w + 2048);     // 8 ints
  int*   hist     = (int*)(w + 2304);     // NE*NGRP ints (4 KB)
  size_t off = 2304 + (size_t)NE * NGRP * 4;
  int*   tok_list = (int*)(w + off);  off += (size_t)SLOTS * 4;
  float* tok_w    = (float*)(w + off); off += (size_t)SLOTS * 4;
  int*   slot_of  = (int*)(w + off);  off += (size_t)TOK * 8;
  int*   epair    = (int*)(w + off);  off += (size_t)TOK * 4;
  float* w1buf    = (float*)(w + off); off += (size_t)TOK * 4;
  off = (off + 255) & ~255ull;
  size_t xh_off = off;
  size_t wh_off = xh_off + (size_t)TOK * HD * 2;
  size_t scr_off = wh_off + (size_t)NE * HD * HD * 2;
  size_t needscr = scr_off + (size_t)SLOTS * HD * 2;
  bool fastscr = ws_size >= needscr;

  if (!fastscr)
    hipMemsetAsync(d_out, 0, (size_t)out_size * sizeof(float), stream);

  _Float16* xh = (_Float16*)(w + xh_off);
  _Float16* wh = (_Float16*)(w + wh_off);
  _Float16* scr = fastscr ? (_Float16*)(w + scr_off) : nullptr;

  score_cvt<<<NGRP + 2048, 256, 0, stream>>>(x, rw, rb, ew, xh, wh,
                                             epair, w1buf, hist);
  moe_scatter<<<NGRP, 256, 0, stream>>>(hist, epair, w1buf, cntp, basep,
                                        tok_list, tok_w, slot_of);

  dim3 grid(HD / 128, TOK / 128, NE);  // (n=8, m<=64, e=8), early-out on m
  if (fastscr) {
    moe_gemm<1><<<grid, 256, 0, stream>>>(xh, wh, eb, cntp, basep,
                                          tok_list, tok_w, scr, out);
    moe_combine<<<TOK / 2, 256, 0, stream>>>(scr, slot_of, out);
  } else {
    moe_gemm<0><<<grid, 256, 0, stream>>>(xh, wh, eb, cntp, basep,
                                          tok_list, tok_w, nullptr, out);
  }
}